// Round 1
// baseline (128.832 us; speedup 1.0000x reference)
//
#include <hip/hip_runtime.h>
#include <stdint.h>

// ---- problem constants ----
#define T_TOK 2048
#define H_DIM 1024
#define I2    1024   // 2*I
#define ID    512    // I
#define E_NUM 8
#define NPAIR 4096   // T_TOK * top_k(2)
#define BM    128
#define BN    128
#define BKK   64
#define MAXTILES 40  // 4096/128 + 8

typedef _Float16 half_t;
typedef _Float16 f16x8 __attribute__((ext_vector_type(8)));
typedef float    f32x4 __attribute__((ext_vector_type(4)));

// ---- workspace layout (bytes) ----
#define XB_OFF      ((size_t)0)                       // f16 [2048][1024]   4 MiB
#define WGU_OFF     ((size_t)4194304)                 // f16 [8][1024][1024] (N=f major, K=h)  16 MiB
#define WDN_OFF     ((size_t)20971520)                // f16 [8][1024][512]  (N=h major, K=i)   8 MiB
#define GU_OFF      ((size_t)29360128)                // f32 [4096][1024]   16 MiB
#define INTER_OFF   ((size_t)46137344)                // f16 [4096][512]     4 MiB
#define CONTRIB_OFF ((size_t)50331648)                // f32 [4096][1024]   16 MiB
#define META_OFF    ((size_t)67108864)                // int meta
#define PAIRW_OFF   ((size_t)67145728)                // f32 [4096]
// meta int layout: [0:8) cnt, [8:16) cursor, [16:25) base, [25] ntiles,
// [32:72) tile_e, [72:112) tile_row0, [112:152) tile_end,
// [160:160+4096) slot_of, [160+4096 : 160+8192) pair_token

__device__ __forceinline__ void gload_lds16(const void* g, void* l) {
    __builtin_amdgcn_global_load_lds(
        (const __attribute__((address_space(1))) unsigned int*)g,
        (__attribute__((address_space(3))) unsigned int*)l,
        16, 0, 0);
}

__global__ void k_meta_init(int* meta) {
    int i = threadIdx.x;
    if (i < 16) meta[i] = 0;   // cnt + cursor
}

__global__ void k_count(const int* ridx, int* meta) {
    int g = blockIdx.x * blockDim.x + threadIdx.x;
    if (g < NPAIR) atomicAdd(&meta[ridx[g]], 1);
}

__global__ void k_plan(int* meta) {
    if (threadIdx.x == 0) {
        int* cnt  = meta;
        int* base = meta + 16;
        int* te   = meta + 32;
        int* tr0  = meta + 72;
        int* tend = meta + 112;
        int acc = 0, nt = 0;
        for (int e = 0; e < E_NUM; e++) {
            base[e] = acc;
            for (int r = 0; r < cnt[e]; r += BM) {
                te[nt] = e; tr0[nt] = acc + r; tend[nt] = acc + cnt[e]; nt++;
            }
            acc += cnt[e];
        }
        base[E_NUM] = acc;
        meta[25] = nt;
    }
}

__global__ void k_scatter(const int* ridx, const float* rw, int* meta, float* pair_w) {
    int g = blockIdx.x * blockDim.x + threadIdx.x;
    if (g >= NPAIR) return;
    int e = ridx[g];
    int pos = atomicAdd(&meta[8 + e], 1);
    int slot = meta[16 + e] + pos;
    meta[160 + g] = slot;                 // slot_of[t*2+k]
    meta[160 + NPAIR + slot] = g >> 1;    // pair_token[slot] = t
    pair_w[slot] = rw[g];
}

__global__ void k_cvt_x(const float* __restrict__ x, half_t* __restrict__ xb) {
    int g = blockIdx.x * blockDim.x + threadIdx.x;   // one per 8 elems
    size_t b0 = (size_t)g * 8;
    float4 v0 = *(const float4*)(x + b0);
    float4 v1 = *(const float4*)(x + b0 + 4);
    f16x8 o;
    o[0] = (half_t)v0.x; o[1] = (half_t)v0.y; o[2] = (half_t)v0.z; o[3] = (half_t)v0.w;
    o[4] = (half_t)v1.x; o[5] = (half_t)v1.y; o[6] = (half_t)v1.z; o[7] = (half_t)v1.w;
    *(f16x8*)(xb + b0) = o;
}

// transpose-convert: in [e][R][C] f32  ->  out [e][C][R] f16
__global__ void k_cvt_wT(const float* __restrict__ in, half_t* __restrict__ out, int R, int C) {
    __shared__ float tile[32][33];
    int e = blockIdx.z;
    const float* pin = in + (size_t)e * R * C;
    half_t* pout = out + (size_t)e * R * C;
    int c0 = blockIdx.x * 32, r0 = blockIdx.y * 32;
    int tx = threadIdx.x, ty = threadIdx.y;   // 32 x 8
    for (int i = 0; i < 32; i += 8)
        tile[ty + i][tx] = pin[(size_t)(r0 + ty + i) * C + c0 + tx];
    __syncthreads();
    for (int i = 0; i < 32; i += 8)
        pout[(size_t)(c0 + ty + i) * R + r0 + tx] = (half_t)tile[tx][ty + i];
}

// MODE 0: A = xb gathered rows (K=1024), B = wguT, out = gu (f32, raw)
// MODE 1: A = inter rows (K=512),        B = wdnT, out = contrib (f32, * pair_w)
template <int MODE>
__global__ __launch_bounds__(256) void k_gemm(const int* __restrict__ meta,
                                              const half_t* __restrict__ amat,
                                              const half_t* __restrict__ wT,
                                              const float* __restrict__ pair_w,
                                              float* __restrict__ outbuf) {
    constexpr int KSZ = MODE ? ID : H_DIM;
    int nt = meta[25];
    int bx = blockIdx.x;
    if (bx >= nt) return;
    int e    = meta[32 + bx];
    int row0 = meta[72 + bx];
    int rend = meta[112 + bx];
    int n0   = blockIdx.y * BN;
    const int* pair_token = meta + 160 + NPAIR;

    __shared__ half_t As[BM * BKK];   // logical [128][64], 16B-chunk XOR-swizzled
    __shared__ half_t Bs[BN * BKK];

    int tid = threadIdx.x;
    int lane = tid & 63, wid = tid >> 6;
    int wm = wid >> 1, wn = wid & 1;

    const half_t* wbase = wT + (size_t)e * 1024 * KSZ;

    // precompute staging sources (fixed per j; only kt advances)
    const half_t* asrc[4];
    const half_t* bsrc[4];
    char* adst[4];
    char* bdst[4];
#pragma unroll
    for (int j = 0; j < 4; j++) {
        int chunk = wid * 4 + j;
        int r  = chunk * 8 + (lane >> 3);
        int lc = (lane & 7) ^ (r & 7);          // swizzled logical k-chunk
        int pr = row0 + r; pr = pr < NPAIR ? pr : NPAIR - 1;
        if (MODE == 0) {
            int tok = pair_token[pr];
            asrc[j] = amat + (size_t)tok * KSZ + lc * 8;
        } else {
            asrc[j] = amat + (size_t)pr * KSZ + lc * 8;
        }
        bsrc[j] = wbase + (size_t)(n0 + r) * KSZ + lc * 8;
        adst[j] = (char*)As + chunk * 1024;
        bdst[j] = (char*)Bs + chunk * 1024;
    }

    f32x4 acc[4][4] = {};

    for (int kt = 0; kt < KSZ / BKK; kt++) {
        __syncthreads();
#pragma unroll
        for (int j = 0; j < 4; j++) {
            gload_lds16(asrc[j] + kt * BKK, adst[j]);
            gload_lds16(bsrc[j] + kt * BKK, bdst[j]);
        }
        __syncthreads();
#pragma unroll
        for (int ks = 0; ks < 2; ks++) {
            f16x8 af[4], bfr[4];
#pragma unroll
            for (int f = 0; f < 4; f++) {
                int ar  = wm * 64 + f * 16 + (lane & 15);
                int apc = (ks * 4 + (lane >> 4)) ^ (ar & 7);
                af[f] = *(const f16x8*)((const char*)As + ar * 128 + apc * 16);
                int br  = wn * 64 + f * 16 + (lane & 15);
                int bpc = (ks * 4 + (lane >> 4)) ^ (br & 7);
                bfr[f] = *(const f16x8*)((const char*)Bs + br * 128 + bpc * 16);
            }
#pragma unroll
            for (int fm = 0; fm < 4; fm++)
#pragma unroll
                for (int fn = 0; fn < 4; fn++)
                    acc[fm][fn] = __builtin_amdgcn_mfma_f32_16x16x32_f16(af[fm], bfr[fn], acc[fm][fn], 0, 0, 0);
        }
    }

    // epilogue: C/D layout col = lane&15, row = (lane>>4)*4 + j
#pragma unroll
    for (int fm = 0; fm < 4; fm++) {
        int rbase = wm * 64 + fm * 16 + (lane >> 4) * 4;
#pragma unroll
        for (int j = 0; j < 4; j++) {
            int packed = row0 + rbase + j;
            if (packed < rend) {
                float pw = MODE ? pair_w[packed] : 1.0f;
#pragma unroll
                for (int fn = 0; fn < 4; fn++) {
                    int col = n0 + wn * 64 + fn * 16 + (lane & 15);
                    float v = acc[fm][fn][j];
                    if (MODE) v *= pw;
                    outbuf[(size_t)packed * 1024 + col] = v;
                }
            }
        }
    }
}

__global__ void k_swiglu(const float* __restrict__ gu, half_t* __restrict__ inter) {
    int g = blockIdx.x * blockDim.x + threadIdx.x;   // one per 8 elems of inter
    int r  = g >> 6;            // 64 chunks of 8 per 512-row
    int c8 = (g & 63) * 8;
    const float* grow = gu + (size_t)r * I2;
    float4 g0 = *(const float4*)(grow + c8);
    float4 g1 = *(const float4*)(grow + c8 + 4);
    float4 u0 = *(const float4*)(grow + ID + c8);
    float4 u1 = *(const float4*)(grow + ID + c8 + 4);
    float gg[8] = {g0.x, g0.y, g0.z, g0.w, g1.x, g1.y, g1.z, g1.w};
    float uu[8] = {u0.x, u0.y, u0.z, u0.w, u1.x, u1.y, u1.z, u1.w};
    f16x8 o;
#pragma unroll
    for (int i = 0; i < 8; i++) {
        float s = gg[i] / (1.0f + __expf(-gg[i]));
        o[i] = (half_t)(s * uu[i]);
    }
    *(f16x8*)(inter + (size_t)r * ID + c8) = o;
}

__global__ void k_gather(const float* __restrict__ contrib, const int* __restrict__ meta,
                         float* __restrict__ out) {
    int g = blockIdx.x * blockDim.x + threadIdx.x;   // one per 4 elems of out
    int t  = g >> 8;            // 256 chunks of 4 per 1024-row
    int c4 = (g & 255) * 4;
    int s0 = meta[160 + t * 2];
    int s1 = meta[160 + t * 2 + 1];
    float4 a = *(const float4*)(contrib + (size_t)s0 * 1024 + c4);
    float4 b = *(const float4*)(contrib + (size_t)s1 * 1024 + c4);
    float4 o;
    o.x = a.x + b.x; o.y = a.y + b.y; o.z = a.z + b.z; o.w = a.w + b.w;
    *(float4*)(out + (size_t)t * 1024 + c4) = o;
}

extern "C" void kernel_launch(void* const* d_in, const int* in_sizes, int n_in,
                              void* d_out, int out_size, void* d_ws, size_t ws_size,
                              hipStream_t stream) {
    const float* x    = (const float*)d_in[0];
    const int*   ridx = (const int*)d_in[1];
    const float* rw   = (const float*)d_in[2];
    const float* wgu  = (const float*)d_in[3];
    const float* wdn  = (const float*)d_in[4];
    float* out = (float*)d_out;

    char* ws = (char*)d_ws;
    half_t* xb      = (half_t*)(ws + XB_OFF);
    half_t* wguT    = (half_t*)(ws + WGU_OFF);
    half_t* wdnT    = (half_t*)(ws + WDN_OFF);
    float*  gu      = (float*)(ws + GU_OFF);
    half_t* inter   = (half_t*)(ws + INTER_OFF);
    float*  contrib = (float*)(ws + CONTRIB_OFF);
    int*    meta    = (int*)(ws + META_OFF);
    float*  pair_w  = (float*)(ws + PAIRW_OFF);

    k_meta_init<<<1, 64, 0, stream>>>(meta);
    k_count<<<NPAIR / 256, 256, 0, stream>>>(ridx, meta);
    k_plan<<<1, 64, 0, stream>>>(meta);
    k_scatter<<<NPAIR / 256, 256, 0, stream>>>(ridx, rw, meta, pair_w);

    k_cvt_x<<<(T_TOK * H_DIM / 8) / 256, 256, 0, stream>>>(x, xb);
    k_cvt_wT<<<dim3(I2 / 32, H_DIM / 32, E_NUM), dim3(32, 8), 0, stream>>>(wgu, wguT, H_DIM, I2);
    k_cvt_wT<<<dim3(H_DIM / 32, ID / 32, E_NUM), dim3(32, 8), 0, stream>>>(wdn, wdnT, ID, H_DIM);

    k_gemm<0><<<dim3(MAXTILES, I2 / BN), 256, 0, stream>>>(meta, xb, wguT, pair_w, gu);
    k_swiglu<<<(NPAIR * ID / 8) / 256, 256, 0, stream>>>(gu, inter);
    k_gemm<1><<<dim3(MAXTILES, H_DIM / BN), 256, 0, stream>>>(meta, inter, wdnT, pair_w, contrib);
    k_gather<<<(T_TOK * H_DIM / 4) / 256, 256, 0, stream>>>(contrib, meta, out);
}

// Round 4
// 83.791 us; speedup vs baseline: 1.5375x; 1.5375x over previous
//
#include <hip/hip_runtime.h>
#include <stdint.h>

// ---- problem constants ----
#define T_TOK 2048
#define H_DIM 1024
#define I2    1024   // 2*I
#define ID    512    // I
#define E_NUM 8
#define NPAIR 4096   // T_TOK * top_k(2)
#define BM    64
#define MAXTILES 72  // sum ceil(cnt_e/64) <= 64 + 7

typedef _Float16 half_t;
typedef _Float16 f16x8 __attribute__((ext_vector_type(8)));
typedef float    f32x4 __attribute__((ext_vector_type(4)));

// ---- workspace layout (bytes) ----
#define XB_OFF    ((size_t)0)               // f16 [2048][1024]    4 MiB
#define WGU_OFF   ((size_t)(4u << 20))      // f16 [8][1024][1024] (f-major, k=h contig) 16 MiB
#define WDN_OFF   ((size_t)(20u << 20))     // f16 [8][1024][512]  (h-major, k=i contig)  8 MiB
#define INTER_OFF ((size_t)(28u << 20))     // f16 [4096][512]     4 MiB
#define META_OFF  ((size_t)(32u << 20))     // ints
#define PAIRW_OFF ((size_t)((32u << 20) + 32768))
// meta: [0]=ntiles, [8..80) tile_e, [88..160) tile_row0, [168..240) tile_end,
//       [256..256+4096) pair_token

__device__ __forceinline__ void gload_lds16(const void* g, void* l) {
    __builtin_amdgcn_global_load_lds(
        (const __attribute__((address_space(1))) unsigned int*)g,
        (__attribute__((address_space(3))) unsigned int*)l,
        16, 0, 0);
}

// ---- routing: count + tile-plan + scatter, one block ----
__global__ __launch_bounds__(1024) void k_route(const int* __restrict__ ridx,
                                                const float* __restrict__ rw,
                                                int* __restrict__ meta,
                                                float* __restrict__ pair_w) {
    __shared__ int cnt[E_NUM], cur[E_NUM], base[E_NUM];
    int tid = threadIdx.x;
    if (tid < E_NUM) { cnt[tid] = 0; cur[tid] = 0; }
    __syncthreads();
    for (int i = tid; i < NPAIR; i += 1024) atomicAdd(&cnt[ridx[i]], 1);
    __syncthreads();
    if (tid == 0) {
        int acc = 0, nt = 0;
        for (int e = 0; e < E_NUM; e++) {
            base[e] = acc;
            for (int r = 0; r < cnt[e]; r += BM) {
                meta[8 + nt] = e; meta[88 + nt] = acc + r; meta[168 + nt] = acc + cnt[e]; nt++;
            }
            acc += cnt[e];
        }
        meta[0] = nt;
    }
    __syncthreads();
    for (int i = tid; i < NPAIR; i += 1024) {
        int e = ridx[i];
        int pos = atomicAdd(&cur[e], 1);
        int slot = base[e] + pos;
        meta[256 + slot] = i >> 1;   // pair_token
        pair_w[slot] = rw[i];
    }
}

__global__ void k_cvt_x(const float* __restrict__ x, half_t* __restrict__ xb) {
    int g = blockIdx.x * blockDim.x + threadIdx.x;   // one per 8 elems
    size_t b0 = (size_t)g * 8;
    float4 v0 = *(const float4*)(x + b0);
    float4 v1 = *(const float4*)(x + b0 + 4);
    f16x8 o;
    o[0] = (half_t)v0.x; o[1] = (half_t)v0.y; o[2] = (half_t)v0.z; o[3] = (half_t)v0.w;
    o[4] = (half_t)v1.x; o[5] = (half_t)v1.y; o[6] = (half_t)v1.z; o[7] = (half_t)v1.w;
    *(f16x8*)(xb + b0) = o;
}

// transpose-convert both weights: z<8 -> gate_up expert z (1024x1024),
// z>=8 -> down expert z-8 (512x1024). in [R][C] f32 -> out [C][R] f16.
__global__ void k_cvt_w(const float* __restrict__ wgu, const float* __restrict__ wdn,
                        half_t* __restrict__ wguT, half_t* __restrict__ wdnT) {
    __shared__ float tile[32][33];
    int z = blockIdx.z;
    const float* pin; half_t* pout; int R;
    const int C = 1024;
    if (z < 8) {
        R = 1024;
        pin = wgu + (size_t)z * R * C;
        pout = wguT + (size_t)z * R * C;
    } else {
        R = 512;
        if (blockIdx.y >= 16) return;
        pin = wdn + (size_t)(z - 8) * R * C;
        pout = wdnT + (size_t)(z - 8) * R * C;
    }
    int c0 = blockIdx.x * 32, r0 = blockIdx.y * 32;
    int tx = threadIdx.x, ty = threadIdx.y;   // 32 x 8
    for (int i = 0; i < 32; i += 8)
        tile[ty + i][tx] = pin[(size_t)(r0 + ty + i) * C + c0 + tx];
    __syncthreads();
    for (int i = 0; i < 32; i += 8)
        pout[(size_t)(c0 + ty + i) * R + r0 + tx] = (half_t)tile[tx][ty + i];
}

// MODE 0: A = xb gathered rows (K=1024), B = wguT; epilogue = in-register SwiGLU
//         -> inter f16. Block covers 64 gate cols (by*64..) + their paired up cols (+512).
// MODE 1: A = inter (K=512), B = wdnT; epilogue = device-scope atomicAdd(out[token], acc*pair_w).
template <int MODE>
__global__ __launch_bounds__(256) void k_gemm(const int* __restrict__ meta,
                                              const half_t* __restrict__ amat,
                                              const half_t* __restrict__ wT,
                                              const float* __restrict__ pair_w,
                                              void* __restrict__ outp) {
    constexpr int KSZ = MODE ? ID : H_DIM;
    constexpr int NKT = KSZ / 64;
    int nt = meta[0];
    int bx = blockIdx.x;
    if (bx >= nt) return;
    int e = meta[8 + bx], row0 = meta[88 + bx], rend = meta[168 + bx];
    int by = blockIdx.y;
    const int* pair_token = meta + 256;

    __shared__ half_t As[64 * 64];    // 8 KiB, [64 rows][8 kchunks], XOR-swizzled
    __shared__ half_t Bs[128 * 64];   // 16 KiB

    int tid = threadIdx.x, lane = tid & 63, wid = tid >> 6;

    // staging sources (16B chunks; swizzle on the global source, linear LDS dest)
    const half_t* asrc[2]; char* adst[2];
#pragma unroll
    for (int i = 0; i < 2; i++) {
        int gch = wid * 2 + i, c = gch * 64 + lane;
        int r = c >> 3, pc = c & 7, lc = pc ^ (r & 7);
        int pr = row0 + r; if (pr > NPAIR - 1) pr = NPAIR - 1;
        const half_t* rowp = (MODE == 0) ? amat + (size_t)pair_token[pr] * KSZ
                                         : amat + (size_t)pr * KSZ;
        asrc[i] = rowp + lc * 8;
        adst[i] = (char*)As + gch * 1024 + lane * 16;
    }
    const half_t* wbase = wT + (size_t)e * 1024 * KSZ;
    const half_t* bsrc[4]; char* bdst[4];
#pragma unroll
    for (int i = 0; i < 4; i++) {
        int gch = wid * 4 + i, c = gch * 64 + lane;
        int r = c >> 3, pc = c & 7, lc = pc ^ (r & 7);
        int physcol;
        if (MODE == 0) {
            int wn_r = r >> 5, fn_r = (r >> 4) & 1, l = r & 15;
            physcol = by * 64 + wn_r * 16 + l + (fn_r ? 512 : 0);
        } else {
            physcol = by * 128 + r;
        }
        bsrc[i] = wbase + (size_t)physcol * KSZ + lc * 8;
        bdst[i] = (char*)Bs + gch * 1024 + lane * 16;
    }

    f32x4 acc[4][2] = {};

    for (int kt = 0; kt < NKT; kt++) {
        __syncthreads();
#pragma unroll
        for (int i = 0; i < 2; i++) gload_lds16(asrc[i] + kt * 64, adst[i]);
#pragma unroll
        for (int i = 0; i < 4; i++) gload_lds16(bsrc[i] + kt * 64, bdst[i]);
        __syncthreads();
#pragma unroll
        for (int ks = 0; ks < 2; ks++) {
            f16x8 af[4], bf2[2];
#pragma unroll
            for (int f = 0; f < 4; f++) {
                int ar = f * 16 + (lane & 15);
                int apc = (ks * 4 + (lane >> 4)) ^ (ar & 7);
                af[f] = *(const f16x8*)((const char*)As + ar * 128 + apc * 16);
            }
#pragma unroll
            for (int f = 0; f < 2; f++) {
                int br = wid * 32 + f * 16 + (lane & 15);
                int bpc = (ks * 4 + (lane >> 4)) ^ (br & 7);
                bf2[f] = *(const f16x8*)((const char*)Bs + br * 128 + bpc * 16);
            }
#pragma unroll
            for (int fm = 0; fm < 4; fm++)
#pragma unroll
                for (int fn = 0; fn < 2; fn++)
                    acc[fm][fn] = __builtin_amdgcn_mfma_f32_16x16x32_f16(af[fm], bf2[fn], acc[fm][fn], 0, 0, 0);
        }
    }

    // C/D layout: col = lane&15, row = (lane>>4)*4 + j
    if (MODE == 0) {
        half_t* inter = (half_t*)outp;
#pragma unroll
        for (int fm = 0; fm < 4; fm++) {
            int rbase = fm * 16 + (lane >> 4) * 4;
#pragma unroll
            for (int j = 0; j < 4; j++) {
                int packed = row0 + rbase + j;
                if (packed < rend) {
                    float gv = acc[fm][0][j], uv = acc[fm][1][j];
                    float s = gv / (1.0f + __expf(-gv)) * uv;
                    int col = by * 64 + wid * 16 + (lane & 15);
                    inter[(size_t)packed * ID + col] = (half_t)s;
                }
            }
        }
    } else {
        float* out = (float*)outp;
#pragma unroll
        for (int fm = 0; fm < 4; fm++) {
            int rbase = fm * 16 + (lane >> 4) * 4;
#pragma unroll
            for (int j = 0; j < 4; j++) {
                int packed = row0 + rbase + j;
                if (packed < rend) {
                    int t = pair_token[packed];
                    float pw = pair_w[packed];
#pragma unroll
                    for (int fn = 0; fn < 2; fn++) {
                        int col = by * 128 + wid * 32 + fn * 16 + (lane & 15);
                        // device(agent)-scope f32 atomic: forced past the XCD-local L2
                        // (unsafeAtomicAdd raced across XCDs -> lost updates on replay)
                        __hip_atomic_fetch_add(&out[(size_t)t * H_DIM + col],
                                               acc[fm][fn][j] * pw,
                                               __ATOMIC_RELAXED,
                                               __HIP_MEMORY_SCOPE_AGENT);
                    }
                }
            }
        }
    }
}

extern "C" void kernel_launch(void* const* d_in, const int* in_sizes, int n_in,
                              void* d_out, int out_size, void* d_ws, size_t ws_size,
                              hipStream_t stream) {
    const float* x    = (const float*)d_in[0];
    const int*   ridx = (const int*)d_in[1];
    const float* rw   = (const float*)d_in[2];
    const float* wgu  = (const float*)d_in[3];
    const float* wdn  = (const float*)d_in[4];
    float* out = (float*)d_out;

    char* ws = (char*)d_ws;
    half_t* xb    = (half_t*)(ws + XB_OFF);
    half_t* wguT  = (half_t*)(ws + WGU_OFF);
    half_t* wdnT  = (half_t*)(ws + WDN_OFF);
    half_t* inter = (half_t*)(ws + INTER_OFF);
    int*    meta  = (int*)(ws + META_OFF);
    float*  pair_w = (float*)(ws + PAIRW_OFF);

    hipMemsetAsync(d_out, 0, (size_t)T_TOK * H_DIM * sizeof(float), stream);
    k_route<<<1, 1024, 0, stream>>>(ridx, rw, meta, pair_w);
    k_cvt_x<<<(T_TOK * H_DIM / 8) / 256, 256, 0, stream>>>(x, xb);
    k_cvt_w<<<dim3(32, 32, 16), dim3(32, 8), 0, stream>>>(wgu, wdn, wguT, wdnT);

    k_gemm<0><<<dim3(MAXTILES, 8), 256, 0, stream>>>(meta, xb, wguT, pair_w, inter);
    k_gemm<1><<<dim3(MAXTILES, 8), 256, 0, stream>>>(meta, inter, wdnT, pair_w, out);
}

// Round 5
// 83.145 us; speedup vs baseline: 1.5495x; 1.0078x over previous
//
#include <hip/hip_runtime.h>
#include <stdint.h>

// ---- problem constants ----
#define T_TOK 2048
#define H_DIM 1024
#define I2    1024   // 2*I
#define ID    512    // I
#define E_NUM 8
#define NPAIR 4096   // T_TOK * top_k(2)
#define BM    64
#define MAXTILES 72  // sum ceil(cnt_e/64) <= 64 + 7

typedef _Float16 half_t;
typedef _Float16 f16x8 __attribute__((ext_vector_type(8)));
typedef float    f32x4 __attribute__((ext_vector_type(4)));

// ---- workspace layout (bytes) ----
#define XB_OFF    ((size_t)0)               // f16 [2048][1024]    4 MiB
#define WGU_OFF   ((size_t)(4u << 20))      // f16 [8][1024][1024] (f-major, k=h contig) 16 MiB
#define WDN_OFF   ((size_t)(20u << 20))     // f16 [8][1024][512]  (h-major, k=i contig)  8 MiB
#define INTER_OFF ((size_t)(28u << 20))     // f16 [4096][512]     4 MiB
#define META_OFF  ((size_t)(32u << 20))     // ints
#define PAIRW_OFF ((size_t)((32u << 20) + 32768))
// meta: [0]=ntiles, [8..80) tile_e, [88..160) tile_row0, [168..240) tile_end,
//       [256..256+4096) pair_token

__device__ __forceinline__ void gload_lds16(const void* g, void* l) {
    __builtin_amdgcn_global_load_lds(
        (const __attribute__((address_space(1))) unsigned int*)g,
        (__attribute__((address_space(3))) unsigned int*)l,
        16, 0, 0);
}

// zero d_out: 2048 blocks x 256 threads x 16B = 8 MiB exactly
// (hipMemsetAsync's fillBuffer kernel ran at 207 GB/s = 40 us/replay)
__global__ void k_zero(float4* __restrict__ p) {
    p[blockIdx.x * 256 + threadIdx.x] = make_float4(0.f, 0.f, 0.f, 0.f);
}

// ---- routing: count + tile-plan + scatter, one block ----
__global__ __launch_bounds__(1024) void k_route(const int* __restrict__ ridx,
                                                const float* __restrict__ rw,
                                                int* __restrict__ meta,
                                                float* __restrict__ pair_w) {
    __shared__ int cnt[E_NUM], cur[E_NUM], base[E_NUM];
    int tid = threadIdx.x;
    if (tid < E_NUM) { cnt[tid] = 0; cur[tid] = 0; }
    __syncthreads();
    for (int i = tid; i < NPAIR; i += 1024) atomicAdd(&cnt[ridx[i]], 1);
    __syncthreads();
    if (tid == 0) {
        int acc = 0, nt = 0;
        for (int e = 0; e < E_NUM; e++) {
            base[e] = acc;
            for (int r = 0; r < cnt[e]; r += BM) {
                meta[8 + nt] = e; meta[88 + nt] = acc + r; meta[168 + nt] = acc + cnt[e]; nt++;
            }
            acc += cnt[e];
        }
        meta[0] = nt;
    }
    __syncthreads();
    for (int i = tid; i < NPAIR; i += 1024) {
        int e = ridx[i];
        int pos = atomicAdd(&cur[e], 1);
        int slot = base[e] + pos;
        meta[256 + slot] = i >> 1;   // pair_token
        pair_w[slot] = rw[i];
    }
}

__global__ void k_cvt_x(const float* __restrict__ x, half_t* __restrict__ xb) {
    int g = blockIdx.x * blockDim.x + threadIdx.x;   // one per 8 elems
    size_t b0 = (size_t)g * 8;
    float4 v0 = *(const float4*)(x + b0);
    float4 v1 = *(const float4*)(x + b0 + 4);
    f16x8 o;
    o[0] = (half_t)v0.x; o[1] = (half_t)v0.y; o[2] = (half_t)v0.z; o[3] = (half_t)v0.w;
    o[4] = (half_t)v1.x; o[5] = (half_t)v1.y; o[6] = (half_t)v1.z; o[7] = (half_t)v1.w;
    *(f16x8*)(xb + b0) = o;
}

// transpose-convert both weights: z<8 -> gate_up expert z (1024x1024),
// z>=8 -> down expert z-8 (512x1024). in [R][C] f32 -> out [C][R] f16.
__global__ void k_cvt_w(const float* __restrict__ wgu, const float* __restrict__ wdn,
                        half_t* __restrict__ wguT, half_t* __restrict__ wdnT) {
    __shared__ float tile[32][33];
    int z = blockIdx.z;
    const float* pin; half_t* pout; int R;
    const int C = 1024;
    if (z < 8) {
        R = 1024;
        pin = wgu + (size_t)z * R * C;
        pout = wguT + (size_t)z * R * C;
    } else {
        R = 512;
        if (blockIdx.y >= 16) return;
        pin = wdn + (size_t)(z - 8) * R * C;
        pout = wdnT + (size_t)(z - 8) * R * C;
    }
    int c0 = blockIdx.x * 32, r0 = blockIdx.y * 32;
    int tx = threadIdx.x, ty = threadIdx.y;   // 32 x 8
    for (int i = 0; i < 32; i += 8)
        tile[ty + i][tx] = pin[(size_t)(r0 + ty + i) * C + c0 + tx];
    __syncthreads();
    for (int i = 0; i < 32; i += 8)
        pout[(size_t)(c0 + ty + i) * R + r0 + tx] = (half_t)tile[tx][ty + i];
}

// MODE 0: A = xb gathered rows (K=1024), B = wguT; epilogue = in-register SwiGLU
//         -> inter f16. Block covers 64 gate cols (by*64..) + their paired up cols (+512).
// MODE 1: A = inter (K=512), B = wdnT; epilogue = device-scope atomicAdd(out[token], acc*pair_w).
template <int MODE>
__global__ __launch_bounds__(256) void k_gemm(const int* __restrict__ meta,
                                              const half_t* __restrict__ amat,
                                              const half_t* __restrict__ wT,
                                              const float* __restrict__ pair_w,
                                              void* __restrict__ outp) {
    constexpr int KSZ = MODE ? ID : H_DIM;
    constexpr int NKT = KSZ / 64;
    int nt = meta[0];
    int bx = blockIdx.x;
    if (bx >= nt) return;
    int e = meta[8 + bx], row0 = meta[88 + bx], rend = meta[168 + bx];
    int by = blockIdx.y;
    const int* pair_token = meta + 256;

    __shared__ half_t As[64 * 64];    // 8 KiB, [64 rows][8 kchunks], XOR-swizzled
    __shared__ half_t Bs[128 * 64];   // 16 KiB

    int tid = threadIdx.x, lane = tid & 63, wid = tid >> 6;

    // staging sources (16B chunks; swizzle on the global source, linear LDS dest)
    const half_t* asrc[2]; char* adst[2];
#pragma unroll
    for (int i = 0; i < 2; i++) {
        int gch = wid * 2 + i, c = gch * 64 + lane;
        int r = c >> 3, pc = c & 7, lc = pc ^ (r & 7);
        int pr = row0 + r; if (pr > NPAIR - 1) pr = NPAIR - 1;
        const half_t* rowp = (MODE == 0) ? amat + (size_t)pair_token[pr] * KSZ
                                         : amat + (size_t)pr * KSZ;
        asrc[i] = rowp + lc * 8;
        adst[i] = (char*)As + gch * 1024 + lane * 16;
    }
    const half_t* wbase = wT + (size_t)e * 1024 * KSZ;
    const half_t* bsrc[4]; char* bdst[4];
#pragma unroll
    for (int i = 0; i < 4; i++) {
        int gch = wid * 4 + i, c = gch * 64 + lane;
        int r = c >> 3, pc = c & 7, lc = pc ^ (r & 7);
        int physcol;
        if (MODE == 0) {
            int wn_r = r >> 5, fn_r = (r >> 4) & 1, l = r & 15;
            physcol = by * 64 + wn_r * 16 + l + (fn_r ? 512 : 0);
        } else {
            physcol = by * 128 + r;
        }
        bsrc[i] = wbase + (size_t)physcol * KSZ + lc * 8;
        bdst[i] = (char*)Bs + gch * 1024 + lane * 16;
    }

    f32x4 acc[4][2] = {};

    for (int kt = 0; kt < NKT; kt++) {
        __syncthreads();
#pragma unroll
        for (int i = 0; i < 2; i++) gload_lds16(asrc[i] + kt * 64, adst[i]);
#pragma unroll
        for (int i = 0; i < 4; i++) gload_lds16(bsrc[i] + kt * 64, bdst[i]);
        __syncthreads();
#pragma unroll
        for (int ks = 0; ks < 2; ks++) {
            f16x8 af[4], bf2[2];
#pragma unroll
            for (int f = 0; f < 4; f++) {
                int ar = f * 16 + (lane & 15);
                int apc = (ks * 4 + (lane >> 4)) ^ (ar & 7);
                af[f] = *(const f16x8*)((const char*)As + ar * 128 + apc * 16);
            }
#pragma unroll
            for (int f = 0; f < 2; f++) {
                int br = wid * 32 + f * 16 + (lane & 15);
                int bpc = (ks * 4 + (lane >> 4)) ^ (br & 7);
                bf2[f] = *(const f16x8*)((const char*)Bs + br * 128 + bpc * 16);
            }
#pragma unroll
            for (int fm = 0; fm < 4; fm++)
#pragma unroll
                for (int fn = 0; fn < 2; fn++)
                    acc[fm][fn] = __builtin_amdgcn_mfma_f32_16x16x32_f16(af[fm], bf2[fn], acc[fm][fn], 0, 0, 0);
        }
    }

    // C/D layout: col = lane&15, row = (lane>>4)*4 + j
    if (MODE == 0) {
        half_t* inter = (half_t*)outp;
#pragma unroll
        for (int fm = 0; fm < 4; fm++) {
            int rbase = fm * 16 + (lane >> 4) * 4;
#pragma unroll
            for (int j = 0; j < 4; j++) {
                int packed = row0 + rbase + j;
                if (packed < rend) {
                    float gv = acc[fm][0][j], uv = acc[fm][1][j];
                    float s = gv / (1.0f + __expf(-gv)) * uv;
                    int col = by * 64 + wid * 16 + (lane & 15);
                    inter[(size_t)packed * ID + col] = (half_t)s;
                }
            }
        }
    } else {
        float* out = (float*)outp;
#pragma unroll
        for (int fm = 0; fm < 4; fm++) {
            int rbase = fm * 16 + (lane >> 4) * 4;
#pragma unroll
            for (int j = 0; j < 4; j++) {
                int packed = row0 + rbase + j;
                if (packed < rend) {
                    int t = pair_token[packed];
                    float pw = pair_w[packed];
#pragma unroll
                    for (int fn = 0; fn < 2; fn++) {
                        int col = by * 128 + wid * 32 + fn * 16 + (lane & 15);
                        // device(agent)-scope f32 atomic: forced past the XCD-local L2
                        // (unsafeAtomicAdd raced across XCDs -> lost updates on replay)
                        __hip_atomic_fetch_add(&out[(size_t)t * H_DIM + col],
                                               acc[fm][fn][j] * pw,
                                               __ATOMIC_RELAXED,
                                               __HIP_MEMORY_SCOPE_AGENT);
                    }
                }
            }
        }
    }
}

extern "C" void kernel_launch(void* const* d_in, const int* in_sizes, int n_in,
                              void* d_out, int out_size, void* d_ws, size_t ws_size,
                              hipStream_t stream) {
    const float* x    = (const float*)d_in[0];
    const int*   ridx = (const int*)d_in[1];
    const float* rw   = (const float*)d_in[2];
    const float* wgu  = (const float*)d_in[3];
    const float* wdn  = (const float*)d_in[4];
    float* out = (float*)d_out;

    char* ws = (char*)d_ws;
    half_t* xb    = (half_t*)(ws + XB_OFF);
    half_t* wguT  = (half_t*)(ws + WGU_OFF);
    half_t* wdnT  = (half_t*)(ws + WDN_OFF);
    half_t* inter = (half_t*)(ws + INTER_OFF);
    int*    meta  = (int*)(ws + META_OFF);
    float*  pair_w = (float*)(ws + PAIRW_OFF);

    k_zero<<<2048, 256, 0, stream>>>((float4*)out);
    k_route<<<1, 1024, 0, stream>>>(ridx, rw, meta, pair_w);
    k_cvt_x<<<(T_TOK * H_DIM / 8) / 256, 256, 0, stream>>>(x, xb);
    k_cvt_w<<<dim3(32, 32, 16), dim3(32, 8), 0, stream>>>(wgu, wdn, wguT, wdnT);

    k_gemm<0><<<dim3(MAXTILES, 8), 256, 0, stream>>>(meta, xb, wguT, pair_w, inter);
    k_gemm<1><<<dim3(MAXTILES, 8), 256, 0, stream>>>(meta, inter, wdnT, pair_w, out);
}

// Round 6
// 77.730 us; speedup vs baseline: 1.6574x; 1.0697x over previous
//
#include <hip/hip_runtime.h>
#include <stdint.h>

// ---- problem constants ----
#define T_TOK 2048
#define H_DIM 1024
#define I2    1024   // 2*I
#define ID    512    // I
#define E_NUM 8
#define NPAIR 4096   // T_TOK * top_k(2)
#define BM    64
#define MAXTILES 72  // sum ceil(cnt_e/64) <= 64 + 7

typedef _Float16 half_t;
typedef _Float16 f16x8 __attribute__((ext_vector_type(8)));
typedef float    f32x4 __attribute__((ext_vector_type(4)));

// ---- workspace layout (bytes) ----
#define XB_OFF    ((size_t)0)               // f16 [2048][1024]    4 MiB
#define WGU_OFF   ((size_t)(4u << 20))      // f16 [8][1024][1024] (f-major, k=h contig) 16 MiB
#define WDN_OFF   ((size_t)(20u << 20))     // f16 [8][1024][512]  (h-major, k=i contig)  8 MiB
#define INTER_OFF ((size_t)(28u << 20))     // f16 [4096][512]     4 MiB
#define META_OFF  ((size_t)(32u << 20))     // ints
#define PAIRW_OFF ((size_t)((32u << 20) + 32768))
// meta: [0]=ntiles, [8..80) tile_e, [88..160) tile_row0, [168..240) tile_end,
//       [256..256+4096) pair_token

__device__ __forceinline__ void gload_lds16(const void* g, void* l) {
    __builtin_amdgcn_global_load_lds(
        (const __attribute__((address_space(1))) unsigned int*)g,
        (__attribute__((address_space(3))) unsigned int*)l,
        16, 0, 0);
}

// ---- fused prep: zero d_out | cvt x->f16 | route ----
__global__ __launch_bounds__(256) void k_prep(const float* __restrict__ x,
                                              const int* __restrict__ ridx,
                                              const float* __restrict__ rw,
                                              half_t* __restrict__ xb,
                                              int* __restrict__ meta,
                                              float* __restrict__ pair_w,
                                              float4* __restrict__ outz) {
    int b = blockIdx.x, tid = threadIdx.x;
    if (b < 512) {
        // zero d_out: 512 blocks * 256 thr * 4 float4 = 8 MiB
        float4 z = make_float4(0.f, 0.f, 0.f, 0.f);
        float4* p = outz + (size_t)b * 1024 + tid;
        p[0] = z; p[256] = z; p[512] = z; p[768] = z;
    } else if (b < 1536) {
        // cvt_x: 1024 blocks, 8 elems/thread
        int g = (b - 512) * 256 + tid;
        size_t b0 = (size_t)g * 8;
        float4 v0 = *(const float4*)(x + b0);
        float4 v1 = *(const float4*)(x + b0 + 4);
        f16x8 o;
        o[0] = (half_t)v0.x; o[1] = (half_t)v0.y; o[2] = (half_t)v0.z; o[3] = (half_t)v0.w;
        o[4] = (half_t)v1.x; o[5] = (half_t)v1.y; o[6] = (half_t)v1.z; o[7] = (half_t)v1.w;
        *(f16x8*)(xb + b0) = o;
    } else {
        // route: one block of 256 threads
        __shared__ int cnt[E_NUM], cur[E_NUM], base[E_NUM];
        if (tid < E_NUM) { cnt[tid] = 0; cur[tid] = 0; }
        __syncthreads();
        for (int i = tid; i < NPAIR; i += 256) atomicAdd(&cnt[ridx[i]], 1);
        __syncthreads();
        if (tid == 0) {
            int acc = 0, nt = 0;
            for (int e = 0; e < E_NUM; e++) {
                base[e] = acc;
                for (int r = 0; r < cnt[e]; r += BM) {
                    meta[8 + nt] = e; meta[88 + nt] = acc + r; meta[168 + nt] = acc + cnt[e]; nt++;
                }
                acc += cnt[e];
            }
            meta[0] = nt;
        }
        __syncthreads();
        for (int i = tid; i < NPAIR; i += 256) {
            int e = ridx[i];
            int pos = atomicAdd(&cur[e], 1);
            int slot = base[e] + pos;
            meta[256 + slot] = i >> 1;   // pair_token
            pair_w[slot] = rw[i];
        }
    }
}

// transpose-convert both weights: z<8 -> gate_up expert z (1024x1024),
// z>=8 -> down expert z-8 (512x1024). in [R][C] f32 -> out [C][R] f16.
__global__ void k_cvt_w(const float* __restrict__ wgu, const float* __restrict__ wdn,
                        half_t* __restrict__ wguT, half_t* __restrict__ wdnT) {
    __shared__ float tile[32][33];
    int z = blockIdx.z;
    const float* pin; half_t* pout; int R;
    const int C = 1024;
    if (z < 8) {
        R = 1024;
        pin = wgu + (size_t)z * R * C;
        pout = wguT + (size_t)z * R * C;
    } else {
        R = 512;
        if (blockIdx.y >= 16) return;
        pin = wdn + (size_t)(z - 8) * R * C;
        pout = wdnT + (size_t)(z - 8) * R * C;
    }
    int c0 = blockIdx.x * 32, r0 = blockIdx.y * 32;
    int tx = threadIdx.x, ty = threadIdx.y;   // 32 x 8
    for (int i = 0; i < 32; i += 8)
        tile[ty + i][tx] = pin[(size_t)(r0 + ty + i) * C + c0 + tx];
    __syncthreads();
    for (int i = 0; i < 32; i += 8)
        pout[(size_t)(c0 + ty + i) * R + r0 + tx] = (half_t)tile[tx][ty + i];
}

// MODE 0: A = xb gathered rows (K=1024), B = wguT; epilogue = in-register SwiGLU -> inter f16.
// MODE 1: A = inter (K=512), B = wdnT; epilogue = agent-scope atomicAdd(out[token], acc*pair_w).
// 1D grid (MAXTILES*8) with XCD swizzle: consecutive row-tiles (same expert) land on the
// same XCD so the expert's weights stay L2-resident. Double-buffered LDS pipeline:
// stage(kt+1) issued BEFORE compute(kt); one barrier (vmcnt drain) per K-step.
template <int MODE>
__global__ __launch_bounds__(256) void k_gemm(const int* __restrict__ meta,
                                              const half_t* __restrict__ amat,
                                              const half_t* __restrict__ wT,
                                              const float* __restrict__ pair_w,
                                              void* __restrict__ outp) {
    constexpr int KSZ = MODE ? ID : H_DIM;
    constexpr int NKT = KSZ / 64;
    int d = blockIdx.x;                       // [0, 576)
    int l = (d & 7) * MAXTILES + (d >> 3);    // XCD c owns l in [c*72, c*72+72)
    int bx = l >> 3, by = l & 7;              // -> 9 consecutive bx (≈1 expert), all by
    int nt = meta[0];
    if (bx >= nt) return;
    int e = meta[8 + bx], row0 = meta[88 + bx], rend = meta[168 + bx];
    const int* pair_token = meta + 256;

    __shared__ half_t As[2][64 * 64];    // 2 x 8 KiB
    __shared__ half_t Bs[2][128 * 64];   // 2 x 16 KiB

    int tid = threadIdx.x, lane = tid & 63, wid = tid >> 6;

    // staging sources (16B chunks; swizzle on the global source, linear LDS dest)
    const half_t* asrc[2]; int aoff[2];
#pragma unroll
    for (int i = 0; i < 2; i++) {
        int gch = wid * 2 + i, c = gch * 64 + lane;
        int r = c >> 3, pc = c & 7, lc = pc ^ (r & 7);
        int pr = row0 + r; if (pr > NPAIR - 1) pr = NPAIR - 1;
        const half_t* rowp = (MODE == 0) ? amat + (size_t)pair_token[pr] * KSZ
                                         : amat + (size_t)pr * KSZ;
        asrc[i] = rowp + lc * 8;
        aoff[i] = gch * 1024 + lane * 16;
    }
    const half_t* wbase = wT + (size_t)e * 1024 * KSZ;
    const half_t* bsrc[4]; int boff[4];
#pragma unroll
    for (int i = 0; i < 4; i++) {
        int gch = wid * 4 + i, c = gch * 64 + lane;
        int r = c >> 3, pc = c & 7, lc = pc ^ (r & 7);
        int physcol;
        if (MODE == 0) {
            int wn_r = r >> 5, fn_r = (r >> 4) & 1, ll = r & 15;
            physcol = by * 64 + wn_r * 16 + ll + (fn_r ? 512 : 0);
        } else {
            physcol = by * 128 + r;
        }
        bsrc[i] = wbase + (size_t)physcol * KSZ + lc * 8;
        boff[i] = gch * 1024 + lane * 16;
    }

#define STAGE(buf, kt)                                                         \
    {                                                                          \
        _Pragma("unroll")                                                      \
        for (int i = 0; i < 2; i++)                                            \
            gload_lds16(asrc[i] + (kt) * 64, (char*)As[buf] + aoff[i]);        \
        _Pragma("unroll")                                                      \
        for (int i = 0; i < 4; i++)                                            \
            gload_lds16(bsrc[i] + (kt) * 64, (char*)Bs[buf] + boff[i]);        \
    }

    f32x4 acc[4][2] = {};

    STAGE(0, 0);
    __syncthreads();   // drains vmcnt(0): buf0 ready

    for (int kt = 0; kt < NKT; kt++) {
        int cur = kt & 1;
        if (kt + 1 < NKT) STAGE(cur ^ 1, kt + 1);   // issue next tile early
#pragma unroll
        for (int ks = 0; ks < 2; ks++) {
            f16x8 af[4], bf2[2];
#pragma unroll
            for (int f = 0; f < 4; f++) {
                int ar = f * 16 + (lane & 15);
                int apc = (ks * 4 + (lane >> 4)) ^ (ar & 7);
                af[f] = *(const f16x8*)((const char*)As[cur] + ar * 128 + apc * 16);
            }
#pragma unroll
            for (int f = 0; f < 2; f++) {
                int br = wid * 32 + f * 16 + (lane & 15);
                int bpc = (ks * 4 + (lane >> 4)) ^ (br & 7);
                bf2[f] = *(const f16x8*)((const char*)Bs[cur] + br * 128 + bpc * 16);
            }
#pragma unroll
            for (int fm = 0; fm < 4; fm++)
#pragma unroll
                for (int fn = 0; fn < 2; fn++)
                    acc[fm][fn] = __builtin_amdgcn_mfma_f32_16x16x32_f16(af[fm], bf2[fn], acc[fm][fn], 0, 0, 0);
        }
        __syncthreads();   // vmcnt(0) drain: next buf ready; all reads of cur done
    }

    // C/D layout: col = lane&15, row = (lane>>4)*4 + j
    if (MODE == 0) {
        half_t* inter = (half_t*)outp;
#pragma unroll
        for (int fm = 0; fm < 4; fm++) {
            int rbase = fm * 16 + (lane >> 4) * 4;
#pragma unroll
            for (int j = 0; j < 4; j++) {
                int packed = row0 + rbase + j;
                if (packed < rend) {
                    float gv = acc[fm][0][j], uv = acc[fm][1][j];
                    float s = gv / (1.0f + __expf(-gv)) * uv;
                    int col = by * 64 + wid * 16 + (lane & 15);
                    inter[(size_t)packed * ID + col] = (half_t)s;
                }
            }
        }
    } else {
        float* out = (float*)outp;
#pragma unroll
        for (int fm = 0; fm < 4; fm++) {
            int rbase = fm * 16 + (lane >> 4) * 4;
#pragma unroll
            for (int j = 0; j < 4; j++) {
                int packed = row0 + rbase + j;
                if (packed < rend) {
                    int t = pair_token[packed];
                    float pw = pair_w[packed];
#pragma unroll
                    for (int fn = 0; fn < 2; fn++) {
                        int col = by * 128 + wid * 32 + fn * 16 + (lane & 15);
                        // agent-scope f32 atomic: coherent across XCDs (unsafeAtomicAdd lost updates)
                        __hip_atomic_fetch_add(&out[(size_t)t * H_DIM + col],
                                               acc[fm][fn][j] * pw,
                                               __ATOMIC_RELAXED,
                                               __HIP_MEMORY_SCOPE_AGENT);
                    }
                }
            }
        }
    }
#undef STAGE
}

extern "C" void kernel_launch(void* const* d_in, const int* in_sizes, int n_in,
                              void* d_out, int out_size, void* d_ws, size_t ws_size,
                              hipStream_t stream) {
    const float* x    = (const float*)d_in[0];
    const int*   ridx = (const int*)d_in[1];
    const float* rw   = (const float*)d_in[2];
    const float* wgu  = (const float*)d_in[3];
    const float* wdn  = (const float*)d_in[4];
    float* out = (float*)d_out;

    char* ws = (char*)d_ws;
    half_t* xb    = (half_t*)(ws + XB_OFF);
    half_t* wguT  = (half_t*)(ws + WGU_OFF);
    half_t* wdnT  = (half_t*)(ws + WDN_OFF);
    half_t* inter = (half_t*)(ws + INTER_OFF);
    int*    meta  = (int*)(ws + META_OFF);
    float*  pair_w = (float*)(ws + PAIRW_OFF);

    k_prep<<<1537, 256, 0, stream>>>(x, ridx, rw, xb, meta, pair_w, (float4*)out);
    k_cvt_w<<<dim3(32, 32, 16), dim3(32, 8), 0, stream>>>(wgu, wdn, wguT, wdnT);

    k_gemm<0><<<MAXTILES * 8, 256, 0, stream>>>(meta, xb, wguT, pair_w, inter);
    k_gemm<1><<<MAXTILES * 8, 256, 0, stream>>>(meta, inter, wdnT, pair_w, out);
}

// Round 8
// 64.610 us; speedup vs baseline: 1.9940x; 1.2031x over previous
//
#include <hip/hip_runtime.h>
#include <stdint.h>

// ---- problem constants ----
#define T_TOK 2048
#define H_DIM 1024
#define ID    512    // I
#define E_NUM 8
#define NPAIR 4096   // T_TOK * top_k(2)
#define BM    64
#define MAXTILES 72  // sum ceil(cnt_e/64) <= 64 + 7

typedef _Float16 half_t;
typedef _Float16 f16x8 __attribute__((ext_vector_type(8)));
typedef _Float16 f16x4 __attribute__((ext_vector_type(4)));
typedef float    f32x4 __attribute__((ext_vector_type(4)));

// ---- workspace layout (bytes) ----
#define XB_OFF    ((size_t)0)               // f16 [2048][1024]    4 MiB
#define WGU_OFF   ((size_t)(4u << 20))      // f16 [8][1024][1024] (f-major, k=h contig) 16 MiB
#define WDN_OFF   ((size_t)(20u << 20))     // f16 [8][1024][512]  (h-major, k=i contig)  8 MiB
#define INTER_OFF ((size_t)(28u << 20))     // f16 [4096][512]     4 MiB
#define META_OFF  ((size_t)(32u << 20))     // ints
#define PAIRW_OFF ((size_t)((32u << 20) + 32768))
// meta: [0]=ntiles, [8..80) tile_e, [88..160) tile_row0, [168..240) tile_end,
//       [256..256+4096) pair_token

__device__ __forceinline__ void gload_lds16(const void* g, void* l) {
    __builtin_amdgcn_global_load_lds(
        (const __attribute__((address_space(1))) unsigned int*)g,
        (__attribute__((address_space(3))) unsigned int*)l,
        16, 0, 0);
}

// 64x64 transpose-convert tile: reads in[r0+r][c0+c] (row stride 1024, f32),
// writes out[(c0+c)*out_stride + r0 + r] (f16). smem >= 64*65*4 bytes.
__device__ __forceinline__ void cvt_tile64(const float* __restrict__ in,
                                           half_t* __restrict__ out,
                                           int r0, int c0, int out_stride,
                                           char* smem) {
    float (*tile)[65] = (float(*)[65])smem;
    int tid = threadIdx.x;
#pragma unroll
    for (int it = 0; it < 4; it++) {
        int idx = tid + it * 256;
        int r = idx >> 4, c4 = (idx & 15) * 4;
        float4 v = *(const float4*)(in + (size_t)(r0 + r) * 1024 + c0 + c4);
        tile[r][c4] = v.x; tile[r][c4 + 1] = v.y; tile[r][c4 + 2] = v.z; tile[r][c4 + 3] = v.w;
    }
    __syncthreads();
#pragma unroll
    for (int it = 0; it < 4; it++) {
        int idx = tid + it * 256;
        int oc = idx >> 4, r4 = (idx & 15) * 4;
        f16x4 o;
        o[0] = (half_t)tile[r4][oc];
        o[1] = (half_t)tile[r4 + 1][oc];
        o[2] = (half_t)tile[r4 + 2][oc];
        o[3] = (half_t)tile[r4 + 3][oc];
        *(f16x4*)(out + (size_t)(c0 + oc) * out_stride + r0 + r4) = o;
    }
}

// ---- fused prep: cvt x->f16 | route | cvt gate_up weights ----
// grid: [0,1024) cvt_x, [1024] route, [1025, 1025+2048) cvt_wgu
__global__ __launch_bounds__(256) void k_prep(const float* __restrict__ x,
                                              const int* __restrict__ ridx,
                                              const float* __restrict__ rw,
                                              const float* __restrict__ wgu,
                                              half_t* __restrict__ xb,
                                              half_t* __restrict__ wguT,
                                              int* __restrict__ meta,
                                              float* __restrict__ pair_w) {
    __shared__ char smem[16704];
    int b = blockIdx.x, tid = threadIdx.x;
    if (b < 1024) {
        int g = b * 256 + tid;
        size_t b0 = (size_t)g * 8;
        float4 v0 = *(const float4*)(x + b0);
        float4 v1 = *(const float4*)(x + b0 + 4);
        f16x8 o;
        o[0] = (half_t)v0.x; o[1] = (half_t)v0.y; o[2] = (half_t)v0.z; o[3] = (half_t)v0.w;
        o[4] = (half_t)v1.x; o[5] = (half_t)v1.y; o[6] = (half_t)v1.z; o[7] = (half_t)v1.w;
        *(f16x8*)(xb + b0) = o;
    } else if (b == 1024) {
        __shared__ int cnt[E_NUM], cur[E_NUM], base[E_NUM];
        if (tid < E_NUM) { cnt[tid] = 0; cur[tid] = 0; }
        __syncthreads();
        for (int i = tid; i < NPAIR; i += 256) atomicAdd(&cnt[ridx[i]], 1);
        __syncthreads();
        if (tid == 0) {
            int acc = 0, nt = 0;
            for (int e = 0; e < E_NUM; e++) {
                base[e] = acc;
                for (int r = 0; r < cnt[e]; r += BM) {
                    meta[8 + nt] = e; meta[88 + nt] = acc + r; meta[168 + nt] = acc + cnt[e]; nt++;
                }
                acc += cnt[e];
            }
            meta[0] = nt;
        }
        __syncthreads();
        for (int i = tid; i < NPAIR; i += 256) {
            int e = ridx[i];
            int pos = atomicAdd(&cur[e], 1);
            int slot = base[e] + pos;
            meta[256 + slot] = i >> 1;   // pair_token
            pair_w[slot] = rw[i];
        }
    } else {
        int t = b - 1025;                 // [0, 2048): gate_up expert tiles
        int e = t >> 8, rem = t & 255;
        int h0 = (rem >> 4) * 64, f0 = (rem & 15) * 64;
        cvt_tile64(wgu + (size_t)e * 1024 * 1024, wguT + (size_t)e * 1024 * 1024,
                   h0, f0, 1024, smem);
    }
}

// MODE 0: A = xb gathered rows (K=1024), B = wguT; epilogue = in-register SwiGLU -> inter f16.
//         extra blocks: [576,1600) cvt down-proj weights; [1600,2112) zero d_out.
// MODE 1: A = inter (K=512), B = wdnT; epilogue = agent-scope atomicAdd(out[token], acc*pair_w).
// GEMM blocks (d<576): 1D XCD swizzle -> one expert's tiles stay on one XCD (L2-resident
// weights). Double-buffered LDS, stage(kt+1) issued before compute(kt).
template <int MODE>
__global__ __launch_bounds__(256) void k_gemm(const int* __restrict__ meta,
                                              const half_t* __restrict__ amat,
                                              const half_t* __restrict__ wT,
                                              const float* __restrict__ pair_w,
                                              void* __restrict__ outp,
                                              const float* __restrict__ aux_in,
                                              half_t* __restrict__ aux_out,
                                              float4* __restrict__ zero_out) {
    constexpr int KSZ = MODE ? ID : H_DIM;
    constexpr int NKT = KSZ / 64;
    __shared__ char smem[49152];   // [0,16K): As 2 bufs; [16K,48K): Bs 2 bufs; cvt aliases

    int d = blockIdx.x;
    if (MODE == 0 && d >= 576) {
        int d2 = d - 576;
        if (d2 < 1024) {           // cvt down-proj: in [e][512 i][1024 h] -> out [e][h][i]
            int e = d2 >> 7, rem = d2 & 127;
            int h0 = (rem >> 3) * 64, i0 = (rem & 7) * 64;
            cvt_tile64(aux_in + (size_t)e * ID * 1024, aux_out + (size_t)e * 1024 * ID,
                       i0, h0, ID, smem);
        } else {                   // zero d_out: 512 blocks * 16 KiB = 8 MiB
            int z = d2 - 1024;
            float4 zv = make_float4(0.f, 0.f, 0.f, 0.f);
            float4* p = zero_out + (size_t)z * 1024 + threadIdx.x;
            p[0] = zv; p[256] = zv; p[512] = zv; p[768] = zv;
        }
        return;
    }

    int l = (d & 7) * MAXTILES + (d >> 3);    // XCD c owns l in [c*72, c*72+72)
    int bx = l >> 3, by = l & 7;
    int nt = meta[0];
    if (bx >= nt) return;
    int e = meta[8 + bx], row0 = meta[88 + bx], rend = meta[168 + bx];
    const int* pair_token = meta + 256;

    int tid = threadIdx.x, lane = tid & 63, wid = tid >> 6;

    // staging sources (16B chunks; XOR swizzle on the global source, linear LDS dest)
    const half_t* asrc[2]; int aoff[2];
#pragma unroll
    for (int i = 0; i < 2; i++) {
        int gch = wid * 2 + i, c = gch * 64 + lane;
        int r = c >> 3, pc = c & 7, lc = pc ^ (r & 7);
        int pr = row0 + r; if (pr > NPAIR - 1) pr = NPAIR - 1;
        const half_t* rowp = (MODE == 0) ? amat + (size_t)pair_token[pr] * KSZ
                                         : amat + (size_t)pr * KSZ;
        asrc[i] = rowp + lc * 8;
        aoff[i] = gch * 1024 + lane * 16;
    }
    const half_t* wbase = wT + (size_t)e * 1024 * KSZ;
    const half_t* bsrc[4]; int boff[4];
#pragma unroll
    for (int i = 0; i < 4; i++) {
        int gch = wid * 4 + i, c = gch * 64 + lane;
        int r = c >> 3, pc = c & 7, lc = pc ^ (r & 7);
        int physcol;
        if (MODE == 0) {
            int wn_r = r >> 5, fn_r = (r >> 4) & 1, ll = r & 15;
            physcol = by * 64 + wn_r * 16 + ll + (fn_r ? 512 : 0);
        } else {
            physcol = by * 128 + r;
        }
        bsrc[i] = wbase + (size_t)physcol * KSZ + lc * 8;
        boff[i] = gch * 1024 + lane * 16;
    }

#define STAGE(buf, kt)                                                             \
    {                                                                              \
        _Pragma("unroll")                                                          \
        for (int i = 0; i < 2; i++)                                                \
            gload_lds16(asrc[i] + (kt) * 64, smem + (buf) * 8192 + aoff[i]);       \
        _Pragma("unroll")                                                          \
        for (int i = 0; i < 4; i++)                                                \
            gload_lds16(bsrc[i] + (kt) * 64, smem + 16384 + (buf) * 16384 + boff[i]); \
    }

    f32x4 acc[4][2] = {};

    STAGE(0, 0);
    __syncthreads();   // buf0 ready

    for (int kt = 0; kt < NKT; kt++) {
        int cur = kt & 1;
        if (kt + 1 < NKT) STAGE(cur ^ 1, kt + 1);   // issue next tile early
        const char* Ab = smem + cur * 8192;
        const char* Bb = smem + 16384 + cur * 16384;
#pragma unroll
        for (int ks = 0; ks < 2; ks++) {
            f16x8 af[4], bf2[2];
#pragma unroll
            for (int f = 0; f < 4; f++) {
                int ar = f * 16 + (lane & 15);
                int apc = (ks * 4 + (lane >> 4)) ^ (ar & 7);
                af[f] = *(const f16x8*)(Ab + ar * 128 + apc * 16);
            }
#pragma unroll
            for (int f = 0; f < 2; f++) {
                int br = wid * 32 + f * 16 + (lane & 15);
                int bpc = (ks * 4 + (lane >> 4)) ^ (br & 7);
                bf2[f] = *(const f16x8*)(Bb + br * 128 + bpc * 16);
            }
#pragma unroll
            for (int fm = 0; fm < 4; fm++)
#pragma unroll
                for (int fn = 0; fn < 2; fn++)
                    acc[fm][fn] = __builtin_amdgcn_mfma_f32_16x16x32_f16(af[fm], bf2[fn], acc[fm][fn], 0, 0, 0);
        }
        __syncthreads();   // drains vmcnt: next buf ready; all reads of cur done
    }

    // C/D layout: col = lane&15, row = (lane>>4)*4 + j
    if (MODE == 0) {
        half_t* inter = (half_t*)outp;
#pragma unroll
        for (int fm = 0; fm < 4; fm++) {
            int rbase = fm * 16 + (lane >> 4) * 4;
#pragma unroll
            for (int j = 0; j < 4; j++) {
                int packed = row0 + rbase + j;
                if (packed < rend) {
                    float gv = acc[fm][0][j], uv = acc[fm][1][j];
                    float s = gv / (1.0f + __expf(-gv)) * uv;
                    int col = by * 64 + wid * 16 + (lane & 15);
                    inter[(size_t)packed * ID + col] = (half_t)s;
                }
            }
        }
    } else {
        float* out = (float*)outp;
#pragma unroll
        for (int fm = 0; fm < 4; fm++) {
            int rbase = fm * 16 + (lane >> 4) * 4;
#pragma unroll
            for (int j = 0; j < 4; j++) {
                int packed = row0 + rbase + j;
                if (packed < rend) {
                    int t = pair_token[packed];
                    float pw = pair_w[packed];
#pragma unroll
                    for (int fn = 0; fn < 2; fn++) {
                        int col = by * 128 + wid * 32 + fn * 16 + (lane & 15);
                        // agent-scope f32 atomic: coherent across XCDs
                        __hip_atomic_fetch_add(&out[(size_t)t * H_DIM + col],
                                               acc[fm][fn][j] * pw,
                                               __ATOMIC_RELAXED,
                                               __HIP_MEMORY_SCOPE_AGENT);
                    }
                }
            }
        }
    }
#undef STAGE
}

extern "C" void kernel_launch(void* const* d_in, const int* in_sizes, int n_in,
                              void* d_out, int out_size, void* d_ws, size_t ws_size,
                              hipStream_t stream) {
    const float* x    = (const float*)d_in[0];
    const int*   ridx = (const int*)d_in[1];
    const float* rw   = (const float*)d_in[2];
    const float* wgu  = (const float*)d_in[3];
    const float* wdn  = (const float*)d_in[4];
    float* out = (float*)d_out;

    char* ws = (char*)d_ws;
    half_t* xb    = (half_t*)(ws + XB_OFF);
    half_t* wguT  = (half_t*)(ws + WGU_OFF);
    half_t* wdnT  = (half_t*)(ws + WDN_OFF);
    half_t* inter = (half_t*)(ws + INTER_OFF);
    int*    meta  = (int*)(ws + META_OFF);
    float*  pair_w = (float*)(ws + PAIRW_OFF);

    // L1: cvt_x (1024) | route (1) | cvt gate_up (2048)
    k_prep<<<3073, 256, 0, stream>>>(x, ridx, rw, wgu, xb, wguT, meta, pair_w);
    // L2: GEMM1 (576) | cvt down (1024) | zero out (512)
    k_gemm<0><<<2112, 256, 0, stream>>>(meta, xb, wguT, pair_w, inter, wdn, wdnT, (float4*)out);
    // L3: GEMM2 (576)
    k_gemm<1><<<576, 256, 0, stream>>>(meta, inter, wdnT, pair_w, out, nullptr, nullptr, nullptr);
}